// Round 1
// baseline (6999.467 us; speedup 1.0000x reference)
//
#include <hip/hip_runtime.h>

#define VOCAB   50000
#define LDIM    8921
#define DDIM    300
#define KSZ     10
#define BATCH   8
#define TSEQ    2048
#define PAD     9          // KSZ-1
#define TPRIME  2057       // TSEQ + KSZ - 1
#define TPADDED 2066       // TSEQ + 2*PAD

// -------- K1: embedding gather + zero-pad into xp[b][d][tau] (B, D, TPADDED)
__global__ __launch_bounds__(256) void gather_pad_kernel(
    const int* __restrict__ ids, const float* __restrict__ embed_w,
    float* __restrict__ xp) {
  int bid = blockIdx.x;
  int dchunk = bid % 4; bid /= 4;
  int tb = bid % 9;     int b = bid / 9;
  int tau = tb * 256 + threadIdx.x;
  if (tau >= TPADDED) return;
  bool inr = (tau >= PAD) && (tau < PAD + TSEQ);
  int row = inr ? ids[b * TSEQ + (tau - PAD)] : 0;
  const float* src = embed_w + (size_t)row * DDIM;
  float* dst = xp + (size_t)b * DDIM * TPADDED + tau;
  int d0 = dchunk * 75;
  for (int d = d0; d < d0 + 75; ++d) {
    dst[(size_t)d * TPADDED] = inr ? src[d] : 0.0f;
  }
}

// -------- K2: conv1d (cross-correlation, padded input) + bias + relu
// h[b,o,t] = relu( bias[o] + sum_{i,k} w[o,i,k] * xp[b,i,t+k] )
// grid: BATCH * 33 blocks; block 256 = 64 t-lanes x 4 o-groups (75 o each)
__global__ __launch_bounds__(256) void conv_relu_kernel(
    const float* __restrict__ xp, const float* __restrict__ w,
    const float* __restrict__ bias, float* __restrict__ h) {
  int b = blockIdx.x / 33, tb = blockIdx.x % 33;
  int lane = threadIdx.x & 63, og = threadIdx.x >> 6;
  int t = tb * 64 + lane;
  int tl = (t < TPRIME) ? t : (TPRIME - 1);
  const float* xpb = xp + (size_t)b * DDIM * TPADDED + tl;
  for (int oc = 0; oc < 5; ++oc) {
    int o0 = og * 75 + oc * 15;
    float acc[15];
#pragma unroll
    for (int j = 0; j < 15; ++j) acc[j] = bias[o0 + j];
    for (int i = 0; i < DDIM; ++i) {
      float xv[KSZ];
      const float* xrow = xpb + (size_t)i * TPADDED;
#pragma unroll
      for (int k = 0; k < KSZ; ++k) xv[k] = xrow[k];
#pragma unroll
      for (int j = 0; j < 15; ++j) {
        const float* wr = w + ((size_t)(o0 + j) * DDIM + i) * KSZ;
#pragma unroll
        for (int k = 0; k < KSZ; ++k) acc[j] = fmaf(wr[k], xv[k], acc[j]);
      }
    }
    if (t < TPRIME) {
      float* hb = h + ((size_t)b * DDIM + o0) * TPRIME + t;
#pragma unroll
      for (int j = 0; j < 15; ++j) hb[(size_t)j * TPRIME] = fmaxf(acc[j], 0.0f);
    }
  }
}

// -------- K3: fused scores + softmax-weighted-mean + bias
// s[b,l,t] = U[l,:] . h[b,:,t];  logit[b,l] = (sum_t e^s * s)/(sum_t e^s) + fcb[l]
// grid: BATCH * 186 (48 l-rows per block); block 256 = 64 t-lanes x 4 l-slices (12 l each)
#define LT 48
#define NLB 186   // ceil(8921/48)
__global__ __launch_bounds__(256) void attn_logits_kernel(
    const float* __restrict__ h, const float* __restrict__ U,
    const float* __restrict__ fcb, float* __restrict__ out) {
  __shared__ float Us[LT][DDIM];
  int b = blockIdx.x / NLB, lb = blockIdx.x % NLB;
  int l0 = lb * LT;
  int tid = threadIdx.x;
  for (int idx = tid; idx < LT * DDIM; idx += 256) {
    int r = idx / DDIM, c = idx % DDIM;
    int l = l0 + r;
    Us[r][c] = (l < LDIM) ? U[(size_t)l * DDIM + c] : 0.0f;
  }
  __syncthreads();
  int lane = tid & 63, sl = tid >> 6;
  const float* hb = h + (size_t)b * DDIM * TPRIME;
  float se[12], sw[12];
#pragma unroll
  for (int j = 0; j < 12; ++j) { se[j] = 0.0f; sw[j] = 0.0f; }
  for (int t0 = 0; t0 < TPRIME; t0 += 128) {
    int t1 = t0 + lane, t2 = t0 + 64 + lane;
    bool v1 = t1 < TPRIME, v2 = t2 < TPRIME;
    int tc1 = v1 ? t1 : 0, tc2 = v2 ? t2 : 0;
    float s1[12], s2[12];
#pragma unroll
    for (int j = 0; j < 12; ++j) { s1[j] = 0.0f; s2[j] = 0.0f; }
    for (int d = 0; d < DDIM; d += 4) {
      float hv1[4], hv2[4];
#pragma unroll
      for (int dd = 0; dd < 4; ++dd) {
        hv1[dd] = hb[(size_t)(d + dd) * TPRIME + tc1];
        hv2[dd] = hb[(size_t)(d + dd) * TPRIME + tc2];
      }
#pragma unroll
      for (int j = 0; j < 12; ++j) {
        const float4 u = *(const float4*)&Us[sl * 12 + j][d];
        s1[j] = fmaf(u.x, hv1[0], s1[j]);
        s1[j] = fmaf(u.y, hv1[1], s1[j]);
        s1[j] = fmaf(u.z, hv1[2], s1[j]);
        s1[j] = fmaf(u.w, hv1[3], s1[j]);
        s2[j] = fmaf(u.x, hv2[0], s2[j]);
        s2[j] = fmaf(u.y, hv2[1], s2[j]);
        s2[j] = fmaf(u.z, hv2[2], s2[j]);
        s2[j] = fmaf(u.w, hv2[3], s2[j]);
      }
    }
#pragma unroll
    for (int j = 0; j < 12; ++j) {
      if (v1) { float e = __expf(s1[j]); se[j] += e; sw[j] = fmaf(e, s1[j], sw[j]); }
      if (v2) { float e = __expf(s2[j]); se[j] += e; sw[j] = fmaf(e, s2[j], sw[j]); }
    }
  }
  // cross-lane (64) reduction
#pragma unroll
  for (int j = 0; j < 12; ++j) {
    for (int off = 32; off > 0; off >>= 1) {
      se[j] += __shfl_down(se[j], off, 64);
      sw[j] += __shfl_down(sw[j], off, 64);
    }
  }
  if (lane == 0) {
#pragma unroll
    for (int j = 0; j < 12; ++j) {
      int l = l0 + sl * 12 + j;
      if (l < LDIM) out[(size_t)b * LDIM + l] = sw[j] / se[j] + fcb[l];
    }
  }
}

extern "C" void kernel_launch(void* const* d_in, const int* in_sizes, int n_in,
                              void* d_out, int out_size, void* d_ws, size_t ws_size,
                              hipStream_t stream) {
  const int*   ids     = (const int*)d_in[0];
  const float* embed_w = (const float*)d_in[1];
  const float* conv_w  = (const float*)d_in[2];
  const float* conv_b  = (const float*)d_in[3];
  const float* U       = (const float*)d_in[4];
  const float* fc_bias = (const float*)d_in[5];
  float* out = (float*)d_out;

  float* xp = (float*)d_ws;                                   // B*D*TPADDED fp32
  float* h  = xp + (size_t)BATCH * DDIM * TPADDED;            // B*D*TPRIME fp32

  hipLaunchKernelGGL(gather_pad_kernel, dim3(BATCH * 9 * 4), dim3(256), 0, stream,
                     ids, embed_w, xp);
  hipLaunchKernelGGL(conv_relu_kernel, dim3(BATCH * 33), dim3(256), 0, stream,
                     xp, conv_w, conv_b, h);
  hipLaunchKernelGGL(attn_logits_kernel, dim3(BATCH * NLB), dim3(256), 0, stream,
                     h, U, fc_bias, out);
}

// Round 2
// 592.617 us; speedup vs baseline: 11.8111x; 11.8111x over previous
//
#include <hip/hip_runtime.h>

#define VOCAB   50000
#define LDIM    8921
#define DDIM    300
#define DPAD    320
#define KSZ     10
#define BATCH   8
#define TSEQ    2048
#define PADL    9
#define TPRIME  2057
#define TPADDED 2066

typedef short s8v __attribute__((ext_vector_type(8)));   // 8 x bf16 bits
typedef float f4v __attribute__((ext_vector_type(4)));

__device__ inline unsigned short f2bf(float f) {
  union { float f; unsigned u; } v; v.f = f;
  unsigned r = v.u + 0x7FFF + ((v.u >> 16) & 1);
  return (unsigned short)(r >> 16);
}

// ---- K1: embedding gather -> xp_bf16[b][tau][DPAD], zero-padded rows/cols
__global__ __launch_bounds__(256) void gather_kernel(
    const int* __restrict__ ids, const float* __restrict__ embed_w,
    unsigned short* __restrict__ xp) {
  int wid = blockIdx.x * 4 + (threadIdx.x >> 6);
  int lane = threadIdx.x & 63;
  int b = wid / TPADDED, tau = wid % TPADDED;
  bool inr = (tau >= PADL) && (tau < PADL + TSEQ);
  int row = inr ? ids[b * TSEQ + (tau - PADL)] : 0;
  const float* src = embed_w + (size_t)row * DDIM;
  unsigned short* dst = xp + ((size_t)b * TPADDED + tau) * DPAD;
  for (int j = 0; j < 5; ++j) {
    int col = j * 64 + lane;
    float v = (inr && col < DDIM) ? src[col] : 0.0f;
    dst[col] = f2bf(v);
  }
}

// ---- K2: conv weight transform -> wT[k][o][i] bf16, o/i padded to 320 with 0
__global__ __launch_bounds__(256) void wt_kernel(
    const float* __restrict__ w, unsigned short* __restrict__ wT) {
  int k = blockIdx.x / DPAD, o = blockIdx.x % DPAD;
  for (int i = threadIdx.x; i < DPAD; i += 256) {
    float v = (o < DDIM && i < DDIM) ? w[((size_t)o * DDIM + i) * KSZ + k] : 0.0f;
    wT[((size_t)k * DPAD + o) * DPAD + i] = f2bf(v);
  }
}

// ---- K3: U transform -> Ub[l][d] bf16, l padded to 8928, d to 320 with 0
#define LPAD 8928
__global__ __launch_bounds__(256) void ut_kernel(
    const float* __restrict__ U, unsigned short* __restrict__ Ub) {
  int l = blockIdx.x;
  for (int d = threadIdx.x; d < DPAD; d += 256) {
    float v = (l < LDIM && d < DDIM) ? U[(size_t)l * DDIM + d] : 0.0f;
    Ub[(size_t)l * DPAD + d] = f2bf(v);
  }
}

// ---- K4: conv via MFMA. h[b][t][o] bf16 (t-major for attn B-frags), relu+bias
#define CTN 64
#define CROWS 73          // CTN + KSZ - 1
#define CSTRIDE 328       // bf16 elems; 656B/row -> 4-bank row offset, ~2-way max
__global__ __launch_bounds__(256, 2) void conv_mfma_kernel(
    const unsigned short* __restrict__ xp, const unsigned short* __restrict__ wT,
    const float* __restrict__ bias, unsigned short* __restrict__ h) {
  __shared__ unsigned short xls[CROWS * CSTRIDE];
  int b = blockIdx.x / 33, tb = blockIdx.x % 33;
  int t0 = tb * CTN;
  int tid = threadIdx.x;
  {
    const unsigned short* src = xp + (size_t)b * TPADDED * DPAD;
    for (int idx = tid; idx < CROWS * (DPAD / 8); idx += 256) {
      int r = idx / 40, c8 = idx % 40;
      int tp = t0 + r;
      int4 v = make_int4(0, 0, 0, 0);
      if (tp < TPADDED) v = *(const int4*)&src[(size_t)tp * DPAD + c8 * 8];
      *(int4*)&xls[r * CSTRIDE + c8 * 8] = v;
    }
  }
  __syncthreads();
  int w = tid >> 6, lane = tid & 63;
  int l15 = lane & 15, quad = lane >> 4;
  f4v acc[5][4];
#pragma unroll
  for (int mf = 0; mf < 5; ++mf) {
    float bv[4];
#pragma unroll
    for (int r = 0; r < 4; ++r) {
      int o = w * 80 + mf * 16 + quad * 4 + r;
      bv[r] = (o < DDIM) ? bias[o] : 0.0f;
    }
#pragma unroll
    for (int nf = 0; nf < 4; ++nf) {
      acc[mf][nf][0] = bv[0]; acc[mf][nf][1] = bv[1];
      acc[mf][nf][2] = bv[2]; acc[mf][nf][3] = bv[3];
    }
  }
  s8v Acur[5], Anext[5];
#pragma unroll
  for (int mf = 0; mf < 5; ++mf)
    Acur[mf] = *(const s8v*)&wT[(size_t)(w * 80 + mf * 16 + l15) * DPAD + quad * 8];
  for (int iter = 0; iter < 100; ++iter) {
    int kc = iter / 10, it = iter % 10;
    if (iter < 99) {
      int kn = (iter + 1) / 10, itn = (iter + 1) % 10;
#pragma unroll
      for (int mf = 0; mf < 5; ++mf)
        Anext[mf] = *(const s8v*)&wT[((size_t)kn * DPAD + w * 80 + mf * 16 + l15) * DPAD + itn * 32 + quad * 8];
    }
    s8v Bv[4];
#pragma unroll
    for (int nf = 0; nf < 4; ++nf) {
      int rrow = nf * 16 + l15 + kc;
      Bv[nf] = *(const s8v*)&xls[rrow * CSTRIDE + it * 32 + quad * 8];
    }
#pragma unroll
    for (int mf = 0; mf < 5; ++mf)
#pragma unroll
      for (int nf = 0; nf < 4; ++nf)
        acc[mf][nf] = __builtin_amdgcn_mfma_f32_16x16x32_bf16(Acur[mf], Bv[nf], acc[mf][nf], 0, 0, 0);
#pragma unroll
    for (int mf = 0; mf < 5; ++mf) Acur[mf] = Anext[mf];
  }
#pragma unroll
  for (int mf = 0; mf < 5; ++mf) {
    int obase = w * 80 + mf * 16 + quad * 4;
#pragma unroll
    for (int nf = 0; nf < 4; ++nf) {
      int t = t0 + nf * 16 + l15;
      if (t < TPRIME) {
        unsigned short pk[4];
#pragma unroll
        for (int r = 0; r < 4; ++r) pk[r] = f2bf(fmaxf(acc[mf][nf][r], 0.0f));
        *(uint2*)&h[((size_t)b * TPRIME + t) * DPAD + obase] = *(uint2*)pk;
      }
    }
  }
}

// ---- K5: scores (U . h) via MFMA + fused softmax-weighted mean
#define ALT 96
#define ASTRIDE 328
#define NLB 93
__global__ __launch_bounds__(256, 2) void attn_mfma_kernel(
    const unsigned short* __restrict__ h, const unsigned short* __restrict__ Ub,
    const float* __restrict__ fcb, float* __restrict__ out) {
  __shared__ unsigned short uls[ALT * ASTRIDE];
  int b = blockIdx.x / NLB, lb = blockIdx.x % NLB;
  int l0 = lb * ALT;
  int tid = threadIdx.x;
  {
    const unsigned short* src = Ub + (size_t)l0 * DPAD;
    for (int idx = tid; idx < ALT * (DPAD / 8); idx += 256) {
      int r = idx / 40, c8 = idx % 40;
      *(int4*)&uls[r * ASTRIDE + c8 * 8] = *(const int4*)&src[(size_t)r * DPAD + c8 * 8];
    }
  }
  __syncthreads();
  int w = tid >> 6, lane = tid & 63;
  int l15 = lane & 15, quad = lane >> 4;
  float se[6][4], sw[6][4];
#pragma unroll
  for (int mf = 0; mf < 6; ++mf)
#pragma unroll
    for (int r = 0; r < 4; ++r) { se[mf][r] = 0.0f; sw[mf][r] = 0.0f; }
  const unsigned short* hb = h + (size_t)b * TPRIME * DPAD;
  for (int t0 = 0; t0 < TPRIME; t0 += 256) {
    int tg[4], tc[4];
#pragma unroll
    for (int nf = 0; nf < 4; ++nf) {
      tg[nf] = t0 + w * 64 + nf * 16 + l15;
      tc[nf] = (tg[nf] < TPRIME) ? tg[nf] : (TPRIME - 1);
    }
    f4v acc[6][4];
#pragma unroll
    for (int mf = 0; mf < 6; ++mf)
#pragma unroll
      for (int nf = 0; nf < 4; ++nf) {
        acc[mf][nf][0] = 0.0f; acc[mf][nf][1] = 0.0f;
        acc[mf][nf][2] = 0.0f; acc[mf][nf][3] = 0.0f;
      }
    for (int kc = 0; kc < 10; ++kc) {
      int koff = kc * 32 + quad * 8;
      s8v Bv[4];
#pragma unroll
      for (int nf = 0; nf < 4; ++nf)
        Bv[nf] = *(const s8v*)&hb[(size_t)tc[nf] * DPAD + koff];
#pragma unroll
      for (int mf = 0; mf < 6; ++mf) {
        s8v Av = *(const s8v*)&uls[(mf * 16 + l15) * ASTRIDE + koff];
#pragma unroll
        for (int nf = 0; nf < 4; ++nf)
          acc[mf][nf] = __builtin_amdgcn_mfma_f32_16x16x32_bf16(Av, Bv[nf], acc[mf][nf], 0, 0, 0);
      }
    }
#pragma unroll
    for (int nf = 0; nf < 4; ++nf) {
      bool valid = tg[nf] < TPRIME;
#pragma unroll
      for (int mf = 0; mf < 6; ++mf)
#pragma unroll
        for (int r = 0; r < 4; ++r) {
          float s = acc[mf][nf][r];
          float e = valid ? __expf(s) : 0.0f;
          se[mf][r] += e;
          sw[mf][r] = fmaf(e, s, sw[mf][r]);
        }
    }
  }
#pragma unroll
  for (int mf = 0; mf < 6; ++mf)
#pragma unroll
    for (int r = 0; r < 4; ++r) {
      float a = se[mf][r], c = sw[mf][r];
#pragma unroll
      for (int off = 1; off < 16; off <<= 1) {
        a += __shfl_xor(a, off, 64);
        c += __shfl_xor(c, off, 64);
      }
      se[mf][r] = a; sw[mf][r] = c;
    }
  __syncthreads();
  float* red = (float*)uls;   // alias: uls no longer needed
  if (l15 == 0) {
#pragma unroll
    for (int mf = 0; mf < 6; ++mf)
#pragma unroll
      for (int r = 0; r < 4; ++r) {
        int row = mf * 16 + quad * 4 + r;
        red[w * ALT + row] = se[mf][r];
        red[4 * ALT + w * ALT + row] = sw[mf][r];
      }
  }
  __syncthreads();
  if (tid < ALT) {
    float a = 0.0f, c = 0.0f;
#pragma unroll
    for (int ww = 0; ww < 4; ++ww) {
      a += red[ww * ALT + tid];
      c += red[4 * ALT + ww * ALT + tid];
    }
    int l = l0 + tid;
    if (l < LDIM) out[(size_t)b * LDIM + l] = c / a + fcb[l];
  }
}

extern "C" void kernel_launch(void* const* d_in, const int* in_sizes, int n_in,
                              void* d_out, int out_size, void* d_ws, size_t ws_size,
                              hipStream_t stream) {
  const int*   ids     = (const int*)d_in[0];
  const float* embed_w = (const float*)d_in[1];
  const float* conv_w  = (const float*)d_in[2];
  const float* conv_b  = (const float*)d_in[3];
  const float* U       = (const float*)d_in[4];
  const float* fc_bias = (const float*)d_in[5];
  float* out = (float*)d_out;

  unsigned char* p = (unsigned char*)d_ws;
  unsigned short* xp = (unsigned short*)p;                 p += (size_t)BATCH * TPADDED * DPAD * 2;
  unsigned short* hb = (unsigned short*)p;                 p += (size_t)BATCH * TPRIME * DPAD * 2;
  unsigned short* wT = (unsigned short*)p;                 p += (size_t)KSZ * DPAD * DPAD * 2;
  unsigned short* Ub = (unsigned short*)p;

  hipLaunchKernelGGL(gather_kernel, dim3(BATCH * TPADDED / 4), dim3(256), 0, stream,
                     ids, embed_w, xp);
  hipLaunchKernelGGL(wt_kernel, dim3(KSZ * DPAD), dim3(256), 0, stream, conv_w, wT);
  hipLaunchKernelGGL(ut_kernel, dim3(LPAD), dim3(256), 0, stream, U, Ub);
  hipLaunchKernelGGL(conv_mfma_kernel, dim3(BATCH * 33), dim3(256), 0, stream,
                     xp, wT, conv_b, hb);
  hipLaunchKernelGGL(attn_mfma_kernel, dim3(BATCH * NLB), dim3(256), 0, stream,
                     hb, Ub, fc_bias, out);
}

// Round 3
// 588.960 us; speedup vs baseline: 11.8845x; 1.0062x over previous
//
#include <hip/hip_runtime.h>

#define VOCAB   50000
#define LDIM    8921
#define DDIM    300
#define DPAD    320
#define KSZ     10
#define BATCH   8
#define TSEQ    2048
#define PADL    9
#define TPRIME  2057
#define TPADDED 2066

typedef short s8v __attribute__((ext_vector_type(8)));   // 8 x bf16 bits
typedef float f4v __attribute__((ext_vector_type(4)));

__device__ inline unsigned short f2bf(float f) {
  union { float f; unsigned u; } v; v.f = f;
  unsigned r = v.u + 0x7FFF + ((v.u >> 16) & 1);
  return (unsigned short)(r >> 16);
}

// ---- K1: embedding gather -> xp_bf16[b][tau][DPAD], zero-padded rows/cols
__global__ __launch_bounds__(256) void gather_kernel(
    const int* __restrict__ ids, const float* __restrict__ embed_w,
    unsigned short* __restrict__ xp) {
  int wid = blockIdx.x * 4 + (threadIdx.x >> 6);
  int lane = threadIdx.x & 63;
  int b = wid / TPADDED, tau = wid % TPADDED;
  bool inr = (tau >= PADL) && (tau < PADL + TSEQ);
  int row = inr ? ids[b * TSEQ + (tau - PADL)] : 0;
  const float* src = embed_w + (size_t)row * DDIM;
  unsigned short* dst = xp + ((size_t)b * TPADDED + tau) * DPAD;
  for (int j = 0; j < 5; ++j) {
    int col = j * 64 + lane;
    float v = (inr && col < DDIM) ? src[col] : 0.0f;
    dst[col] = f2bf(v);
  }
}

// ---- K2: conv weight transform -> wT[k][o][i] bf16, o/i padded to 320 with 0
__global__ __launch_bounds__(256) void wt_kernel(
    const float* __restrict__ w, unsigned short* __restrict__ wT) {
  int k = blockIdx.x / DPAD, o = blockIdx.x % DPAD;
  for (int i = threadIdx.x; i < DPAD; i += 256) {
    float v = (o < DDIM && i < DDIM) ? w[((size_t)o * DDIM + i) * KSZ + k] : 0.0f;
    wT[((size_t)k * DPAD + o) * DPAD + i] = f2bf(v);
  }
}

// ---- K3: U transform -> Ub[l][d] bf16, l padded to 8928, d to 320 with 0
#define LPAD 8928
__global__ __launch_bounds__(256) void ut_kernel(
    const float* __restrict__ U, unsigned short* __restrict__ Ub) {
  int l = blockIdx.x;
  for (int d = threadIdx.x; d < DPAD; d += 256) {
    float v = (l < LDIM && d < DDIM) ? U[(size_t)l * DDIM + d] : 0.0f;
    Ub[(size_t)l * DPAD + d] = f2bf(v);
  }
}

// ---- K4: conv via MFMA. h[b][t][o] bf16 (t-major for attn B-frags), relu+bias
// XCD swizzle: b = blockIdx.x & 7 so batch b lives on XCD b (round-robin map);
// h_b is then written into the same XCD's L2 that attn reads it from.
#define CTN 64
#define CROWS 73          // CTN + KSZ - 1
#define CSTRIDE 328       // bf16 elems; 656B/row -> 4-bank row offset, ~2-way max
__global__ __launch_bounds__(256, 2) void conv_mfma_kernel(
    const unsigned short* __restrict__ xp, const unsigned short* __restrict__ wT,
    const float* __restrict__ bias, unsigned short* __restrict__ h) {
  __shared__ unsigned short xls[CROWS * CSTRIDE];
  int b = blockIdx.x & 7, tb = blockIdx.x >> 3;
  int t0 = tb * CTN;
  int tid = threadIdx.x;
  {
    const unsigned short* src = xp + (size_t)b * TPADDED * DPAD;
    for (int idx = tid; idx < CROWS * (DPAD / 8); idx += 256) {
      int r = idx / 40, c8 = idx % 40;
      int tp = t0 + r;
      int4 v = make_int4(0, 0, 0, 0);
      if (tp < TPADDED) v = *(const int4*)&src[(size_t)tp * DPAD + c8 * 8];
      *(int4*)&xls[r * CSTRIDE + c8 * 8] = v;
    }
  }
  __syncthreads();
  int w = tid >> 6, lane = tid & 63;
  int l15 = lane & 15, quad = lane >> 4;
  f4v acc[5][4];
#pragma unroll
  for (int mf = 0; mf < 5; ++mf) {
    float bv[4];
#pragma unroll
    for (int r = 0; r < 4; ++r) {
      int o = w * 80 + mf * 16 + quad * 4 + r;
      bv[r] = (o < DDIM) ? bias[o] : 0.0f;
    }
#pragma unroll
    for (int nf = 0; nf < 4; ++nf) {
      acc[mf][nf][0] = bv[0]; acc[mf][nf][1] = bv[1];
      acc[mf][nf][2] = bv[2]; acc[mf][nf][3] = bv[3];
    }
  }
  s8v Acur[5], Anext[5];
#pragma unroll
  for (int mf = 0; mf < 5; ++mf)
    Acur[mf] = *(const s8v*)&wT[(size_t)(w * 80 + mf * 16 + l15) * DPAD + quad * 8];
  for (int iter = 0; iter < 100; ++iter) {
    int kc = iter / 10, it = iter % 10;
    if (iter < 99) {
      int kn = (iter + 1) / 10, itn = (iter + 1) % 10;
#pragma unroll
      for (int mf = 0; mf < 5; ++mf)
        Anext[mf] = *(const s8v*)&wT[((size_t)kn * DPAD + w * 80 + mf * 16 + l15) * DPAD + itn * 32 + quad * 8];
    }
    s8v Bv[4];
#pragma unroll
    for (int nf = 0; nf < 4; ++nf) {
      int rrow = nf * 16 + l15 + kc;
      Bv[nf] = *(const s8v*)&xls[rrow * CSTRIDE + it * 32 + quad * 8];
    }
#pragma unroll
    for (int mf = 0; mf < 5; ++mf)
#pragma unroll
      for (int nf = 0; nf < 4; ++nf)
        acc[mf][nf] = __builtin_amdgcn_mfma_f32_16x16x32_bf16(Acur[mf], Bv[nf], acc[mf][nf], 0, 0, 0);
#pragma unroll
    for (int mf = 0; mf < 5; ++mf) Acur[mf] = Anext[mf];
  }
#pragma unroll
  for (int mf = 0; mf < 5; ++mf) {
    int obase = w * 80 + mf * 16 + quad * 4;
#pragma unroll
    for (int nf = 0; nf < 4; ++nf) {
      int t = t0 + nf * 16 + l15;
      if (t < TPRIME) {
        unsigned short pk[4];
#pragma unroll
        for (int r = 0; r < 4; ++r) pk[r] = f2bf(fmaxf(acc[mf][nf][r], 0.0f));
        *(uint2*)&h[((size_t)b * TPRIME + t) * DPAD + obase] = *(uint2*)pk;
      }
    }
  }
}

// ---- K5: scores (U . h) via MFMA + fused softmax-weighted mean
// XCD swizzle: b = blockIdx.x & 7 -> XCD i only streams h_i (1.32 MB, L2-resident).
#define ALT 96
#define ASTRIDE 328
#define NLB 93
__global__ __launch_bounds__(256, 2) void attn_mfma_kernel(
    const unsigned short* __restrict__ h, const unsigned short* __restrict__ Ub,
    const float* __restrict__ fcb, float* __restrict__ out) {
  __shared__ unsigned short uls[ALT * ASTRIDE];
  int b = blockIdx.x & 7, lb = blockIdx.x >> 3;
  int l0 = lb * ALT;
  int tid = threadIdx.x;
  {
    const unsigned short* src = Ub + (size_t)l0 * DPAD;
    for (int idx = tid; idx < ALT * (DPAD / 8); idx += 256) {
      int r = idx / 40, c8 = idx % 40;
      *(int4*)&uls[r * ASTRIDE + c8 * 8] = *(const int4*)&src[(size_t)r * DPAD + c8 * 8];
    }
  }
  __syncthreads();
  int w = tid >> 6, lane = tid & 63;
  int l15 = lane & 15, quad = lane >> 4;
  float se[6][4], sw[6][4];
#pragma unroll
  for (int mf = 0; mf < 6; ++mf)
#pragma unroll
    for (int r = 0; r < 4; ++r) { se[mf][r] = 0.0f; sw[mf][r] = 0.0f; }
  const unsigned short* hb = h + (size_t)b * TPRIME * DPAD;
  for (int t0 = 0; t0 < TPRIME; t0 += 256) {
    int tg[4], tc[4];
#pragma unroll
    for (int nf = 0; nf < 4; ++nf) {
      tg[nf] = t0 + w * 64 + nf * 16 + l15;
      tc[nf] = (tg[nf] < TPRIME) ? tg[nf] : (TPRIME - 1);
    }
    f4v acc[6][4];
#pragma unroll
    for (int mf = 0; mf < 6; ++mf)
#pragma unroll
      for (int nf = 0; nf < 4; ++nf) {
        acc[mf][nf][0] = 0.0f; acc[mf][nf][1] = 0.0f;
        acc[mf][nf][2] = 0.0f; acc[mf][nf][3] = 0.0f;
      }
    for (int kc = 0; kc < 10; ++kc) {
      int koff = kc * 32 + quad * 8;
      s8v Bv[4];
#pragma unroll
      for (int nf = 0; nf < 4; ++nf)
        Bv[nf] = *(const s8v*)&hb[(size_t)tc[nf] * DPAD + koff];
#pragma unroll
      for (int mf = 0; mf < 6; ++mf) {
        s8v Av = *(const s8v*)&uls[(mf * 16 + l15) * ASTRIDE + koff];
#pragma unroll
        for (int nf = 0; nf < 4; ++nf)
          acc[mf][nf] = __builtin_amdgcn_mfma_f32_16x16x32_bf16(Av, Bv[nf], acc[mf][nf], 0, 0, 0);
      }
    }
#pragma unroll
    for (int nf = 0; nf < 4; ++nf) {
      bool valid = tg[nf] < TPRIME;
#pragma unroll
      for (int mf = 0; mf < 6; ++mf)
#pragma unroll
        for (int r = 0; r < 4; ++r) {
          float s = acc[mf][nf][r];
          float e = valid ? __expf(s) : 0.0f;
          se[mf][r] += e;
          sw[mf][r] = fmaf(e, s, sw[mf][r]);
        }
    }
  }
#pragma unroll
  for (int mf = 0; mf < 6; ++mf)
#pragma unroll
    for (int r = 0; r < 4; ++r) {
      float a = se[mf][r], c = sw[mf][r];
#pragma unroll
      for (int off = 1; off < 16; off <<= 1) {
        a += __shfl_xor(a, off, 64);
        c += __shfl_xor(c, off, 64);
      }
      se[mf][r] = a; sw[mf][r] = c;
    }
  __syncthreads();
  float* red = (float*)uls;   // alias: uls no longer needed
  if (l15 == 0) {
#pragma unroll
    for (int mf = 0; mf < 6; ++mf)
#pragma unroll
      for (int r = 0; r < 4; ++r) {
        int row = mf * 16 + quad * 4 + r;
        red[w * ALT + row] = se[mf][r];
        red[4 * ALT + w * ALT + row] = sw[mf][r];
      }
  }
  __syncthreads();
  if (tid < ALT) {
    float a = 0.0f, c = 0.0f;
#pragma unroll
    for (int ww = 0; ww < 4; ++ww) {
      a += red[ww * ALT + tid];
      c += red[4 * ALT + ww * ALT + tid];
    }
    int l = l0 + tid;
    if (l < LDIM) out[(size_t)b * LDIM + l] = c / a + fcb[l];
  }
}

extern "C" void kernel_launch(void* const* d_in, const int* in_sizes, int n_in,
                              void* d_out, int out_size, void* d_ws, size_t ws_size,
                              hipStream_t stream) {
  const int*   ids     = (const int*)d_in[0];
  const float* embed_w = (const float*)d_in[1];
  const float* conv_w  = (const float*)d_in[2];
  const float* conv_b  = (const float*)d_in[3];
  const float* U       = (const float*)d_in[4];
  const float* fc_bias = (const float*)d_in[5];
  float* out = (float*)d_out;

  unsigned char* p = (unsigned char*)d_ws;
  unsigned short* xp = (unsigned short*)p;                 p += (size_t)BATCH * TPADDED * DPAD * 2;
  unsigned short* hb = (unsigned short*)p;                 p += (size_t)BATCH * TPRIME * DPAD * 2;
  unsigned short* wT = (unsigned short*)p;                 p += (size_t)KSZ * DPAD * DPAD * 2;
  unsigned short* Ub = (unsigned short*)p;

  hipLaunchKernelGGL(gather_kernel, dim3(BATCH * TPADDED / 4), dim3(256), 0, stream,
                     ids, embed_w, xp);
  hipLaunchKernelGGL(wt_kernel, dim3(KSZ * DPAD), dim3(256), 0, stream, conv_w, wT);
  hipLaunchKernelGGL(ut_kernel, dim3(LPAD), dim3(256), 0, stream, U, Ub);
  hipLaunchKernelGGL(conv_mfma_kernel, dim3(BATCH * 33), dim3(256), 0, stream,
                     xp, wT, conv_b, hb);
  hipLaunchKernelGGL(attn_mfma_kernel, dim3(BATCH * NLB), dim3(256), 0, stream,
                     hb, Ub, fc_bias, out);
}

// Round 4
// 452.069 us; speedup vs baseline: 15.4832x; 1.3028x over previous
//
#include <hip/hip_runtime.h>

#define VOCAB   50000
#define LDIM    8921
#define DDIM    300
#define DPAD    320
#define KSZ     10
#define BATCH   8
#define TSEQ    2048
#define PADL    9
#define TPRIME  2057
#define TPADDED 2066

typedef short s8v __attribute__((ext_vector_type(8)));   // 8 x bf16 bits
typedef float f4v __attribute__((ext_vector_type(4)));

__device__ inline unsigned short f2bf(float f) {
  union { float f; unsigned u; } v; v.f = f;
  unsigned r = v.u + 0x7FFF + ((v.u >> 16) & 1);
  return (unsigned short)(r >> 16);
}

// ---- K1: embedding gather -> xp_bf16[b][tau][DPAD], zero-padded rows/cols
__global__ __launch_bounds__(256) void gather_kernel(
    const int* __restrict__ ids, const float* __restrict__ embed_w,
    unsigned short* __restrict__ xp) {
  int wid = blockIdx.x * 4 + (threadIdx.x >> 6);
  int lane = threadIdx.x & 63;
  int b = wid / TPADDED, tau = wid % TPADDED;
  bool inr = (tau >= PADL) && (tau < PADL + TSEQ);
  int row = inr ? ids[b * TSEQ + (tau - PADL)] : 0;
  const float* src = embed_w + (size_t)row * DDIM;
  unsigned short* dst = xp + ((size_t)b * TPADDED + tau) * DPAD;
  for (int j = 0; j < 5; ++j) {
    int col = j * 64 + lane;
    float v = (inr && col < DDIM) ? src[col] : 0.0f;
    dst[col] = f2bf(v);
  }
}

// ---- K2: conv weight transform -> wT[k][o][i] bf16, o/i padded to 320 with 0
__global__ __launch_bounds__(256) void wt_kernel(
    const float* __restrict__ w, unsigned short* __restrict__ wT) {
  int k = blockIdx.x / DPAD, o = blockIdx.x % DPAD;
  for (int i = threadIdx.x; i < DPAD; i += 256) {
    float v = (o < DDIM && i < DDIM) ? w[((size_t)o * DDIM + i) * KSZ + k] : 0.0f;
    wT[((size_t)k * DPAD + o) * DPAD + i] = f2bf(v);
  }
}

// ---- K3: U transform -> Ub[l][d] bf16, l padded to 8928, d to 320 with 0
#define LPAD 8928
__global__ __launch_bounds__(256) void ut_kernel(
    const float* __restrict__ U, unsigned short* __restrict__ Ub) {
  int l = blockIdx.x;
  for (int d = threadIdx.x; d < DPAD; d += 256) {
    float v = (l < LDIM && d < DDIM) ? U[(size_t)l * DDIM + d] : 0.0f;
    Ub[(size_t)l * DPAD + d] = f2bf(v);
  }
}

// ---- K4: conv via MFMA. h[b][t][o] bf16 (t-major for attn B-frags), relu+bias
// XCD swizzle: b = blockIdx.x & 7 so batch b lives on XCD b (round-robin map).
#define CTN 64
#define CROWS 73          // CTN + KSZ - 1
#define CSTRIDE 328       // bf16 elems; 656B/row -> 4-bank row offset, ~2-way max
__global__ __launch_bounds__(256, 2) void conv_mfma_kernel(
    const unsigned short* __restrict__ xp, const unsigned short* __restrict__ wT,
    const float* __restrict__ bias, unsigned short* __restrict__ h) {
  __shared__ unsigned short xls[CROWS * CSTRIDE];
  int b = blockIdx.x & 7, tb = blockIdx.x >> 3;
  int t0 = tb * CTN;
  int tid = threadIdx.x;
  {
    const unsigned short* src = xp + (size_t)b * TPADDED * DPAD;
    for (int idx = tid; idx < CROWS * (DPAD / 8); idx += 256) {
      int r = idx / 40, c8 = idx % 40;
      int tp = t0 + r;
      int4 v = make_int4(0, 0, 0, 0);
      if (tp < TPADDED) v = *(const int4*)&src[(size_t)tp * DPAD + c8 * 8];
      *(int4*)&xls[r * CSTRIDE + c8 * 8] = v;
    }
  }
  __syncthreads();
  int w = tid >> 6, lane = tid & 63;
  int l15 = lane & 15, quad = lane >> 4;
  f4v acc[5][4];
#pragma unroll
  for (int mf = 0; mf < 5; ++mf) {
    float bv[4];
#pragma unroll
    for (int r = 0; r < 4; ++r) {
      int o = w * 80 + mf * 16 + quad * 4 + r;
      bv[r] = (o < DDIM) ? bias[o] : 0.0f;
    }
#pragma unroll
    for (int nf = 0; nf < 4; ++nf) {
      acc[mf][nf][0] = bv[0]; acc[mf][nf][1] = bv[1];
      acc[mf][nf][2] = bv[2]; acc[mf][nf][3] = bv[3];
    }
  }
  s8v Acur[5], Anext[5];
#pragma unroll
  for (int mf = 0; mf < 5; ++mf)
    Acur[mf] = *(const s8v*)&wT[(size_t)(w * 80 + mf * 16 + l15) * DPAD + quad * 8];
  for (int iter = 0; iter < 100; ++iter) {
    int kc = iter / 10, it = iter % 10;
    if (iter < 99) {
      int kn = (iter + 1) / 10, itn = (iter + 1) % 10;
#pragma unroll
      for (int mf = 0; mf < 5; ++mf)
        Anext[mf] = *(const s8v*)&wT[((size_t)kn * DPAD + w * 80 + mf * 16 + l15) * DPAD + itn * 32 + quad * 8];
    }
    s8v Bv[4];
#pragma unroll
    for (int nf = 0; nf < 4; ++nf) {
      int rrow = nf * 16 + l15 + kc;
      Bv[nf] = *(const s8v*)&xls[rrow * CSTRIDE + it * 32 + quad * 8];
    }
#pragma unroll
    for (int mf = 0; mf < 5; ++mf)
#pragma unroll
      for (int nf = 0; nf < 4; ++nf)
        acc[mf][nf] = __builtin_amdgcn_mfma_f32_16x16x32_bf16(Acur[mf], Bv[nf], acc[mf][nf], 0, 0, 0);
#pragma unroll
    for (int mf = 0; mf < 5; ++mf) Acur[mf] = Anext[mf];
  }
#pragma unroll
  for (int mf = 0; mf < 5; ++mf) {
    int obase = w * 80 + mf * 16 + quad * 4;
#pragma unroll
    for (int nf = 0; nf < 4; ++nf) {
      int t = t0 + nf * 16 + l15;
      if (t < TPRIME) {
        unsigned short pk[4];
#pragma unroll
        for (int r = 0; r < 4; ++r) pk[r] = f2bf(fmaxf(acc[mf][nf][r], 0.0f));
        *(uint2*)&h[((size_t)b * TPRIME + t) * DPAD + obase] = *(uint2*)pk;
      }
    }
  }
}

// ---- K5: scores (U . h) via MFMA + fused softmax-weighted mean
// nf=2 (128-t tile per block, 32 t per wave) -> ~120 VGPR working set, NO SPILLS.
// XCD swizzle: b = blockIdx.x & 7 -> XCD i streams only h_i (1.32 MB, L2-resident).
#define ALT 96
#define ASTRIDE 328
#define NLB 93
#define ATT 128           // t per block-tile
__global__ __launch_bounds__(256, 3) void attn_mfma_kernel(
    const unsigned short* __restrict__ h, const unsigned short* __restrict__ Ub,
    const float* __restrict__ fcb, float* __restrict__ out) {
  __shared__ unsigned short uls[ALT * ASTRIDE];
  int b = blockIdx.x & 7, lb = blockIdx.x >> 3;
  int l0 = lb * ALT;
  int tid = threadIdx.x;
  {
    const unsigned short* src = Ub + (size_t)l0 * DPAD;
    for (int idx = tid; idx < ALT * (DPAD / 8); idx += 256) {
      int r = idx / 40, c8 = idx % 40;
      *(int4*)&uls[r * ASTRIDE + c8 * 8] = *(const int4*)&src[(size_t)r * DPAD + c8 * 8];
    }
  }
  __syncthreads();
  int w = tid >> 6, lane = tid & 63;
  int l15 = lane & 15, quad = lane >> 4;
  float se[6][4], sw[6][4];
#pragma unroll
  for (int mf = 0; mf < 6; ++mf)
#pragma unroll
    for (int r = 0; r < 4; ++r) { se[mf][r] = 0.0f; sw[mf][r] = 0.0f; }
  const unsigned short* hb = h + (size_t)b * TPRIME * DPAD;
  for (int t0 = 0; t0 < TPRIME; t0 += ATT) {
    int tg[2], tc[2];
#pragma unroll
    for (int nf = 0; nf < 2; ++nf) {
      tg[nf] = t0 + w * 32 + nf * 16 + l15;
      tc[nf] = (tg[nf] < TPRIME) ? tg[nf] : (TPRIME - 1);
    }
    f4v acc[6][2];
#pragma unroll
    for (int mf = 0; mf < 6; ++mf)
#pragma unroll
      for (int nf = 0; nf < 2; ++nf) {
        acc[mf][nf][0] = 0.0f; acc[mf][nf][1] = 0.0f;
        acc[mf][nf][2] = 0.0f; acc[mf][nf][3] = 0.0f;
      }
    for (int kc = 0; kc < 10; ++kc) {
      int koff = kc * 32 + quad * 8;
      s8v Bv[2];
#pragma unroll
      for (int nf = 0; nf < 2; ++nf)
        Bv[nf] = *(const s8v*)&hb[(size_t)tc[nf] * DPAD + koff];
#pragma unroll
      for (int mf = 0; mf < 6; ++mf) {
        s8v Av = *(const s8v*)&uls[(mf * 16 + l15) * ASTRIDE + koff];
#pragma unroll
        for (int nf = 0; nf < 2; ++nf)
          acc[mf][nf] = __builtin_amdgcn_mfma_f32_16x16x32_bf16(Av, Bv[nf], acc[mf][nf], 0, 0, 0);
      }
    }
#pragma unroll
    for (int nf = 0; nf < 2; ++nf) {
      bool valid = tg[nf] < TPRIME;
#pragma unroll
      for (int mf = 0; mf < 6; ++mf)
#pragma unroll
        for (int r = 0; r < 4; ++r) {
          float s = acc[mf][nf][r];
          float e = valid ? __expf(s) : 0.0f;
          se[mf][r] += e;
          sw[mf][r] = fmaf(e, s, sw[mf][r]);
        }
    }
  }
  // reduce over the 16 t-columns within each wave
#pragma unroll
  for (int mf = 0; mf < 6; ++mf)
#pragma unroll
    for (int r = 0; r < 4; ++r) {
      float a = se[mf][r], c = sw[mf][r];
#pragma unroll
      for (int off = 1; off < 16; off <<= 1) {
        a += __shfl_xor(a, off, 64);
        c += __shfl_xor(c, off, 64);
      }
      se[mf][r] = a; sw[mf][r] = c;
    }
  __syncthreads();
  float* red = (float*)uls;   // alias: uls no longer needed
  if (l15 == 0) {
#pragma unroll
    for (int mf = 0; mf < 6; ++mf)
#pragma unroll
      for (int r = 0; r < 4; ++r) {
        int row = mf * 16 + quad * 4 + r;
        red[w * ALT + row] = se[mf][r];
        red[4 * ALT + w * ALT + row] = sw[mf][r];
      }
  }
  __syncthreads();
  if (tid < ALT) {
    float a = 0.0f, c = 0.0f;
#pragma unroll
    for (int ww = 0; ww < 4; ++ww) {
      a += red[ww * ALT + tid];
      c += red[4 * ALT + ww * ALT + tid];
    }
    int l = l0 + tid;
    if (l < LDIM) out[(size_t)b * LDIM + l] = c / a + fcb[l];
  }
}

extern "C" void kernel_launch(void* const* d_in, const int* in_sizes, int n_in,
                              void* d_out, int out_size, void* d_ws, size_t ws_size,
                              hipStream_t stream) {
  const int*   ids     = (const int*)d_in[0];
  const float* embed_w = (const float*)d_in[1];
  const float* conv_w  = (const float*)d_in[2];
  const float* conv_b  = (const float*)d_in[3];
  const float* U       = (const float*)d_in[4];
  const float* fc_bias = (const float*)d_in[5];
  float* out = (float*)d_out;

  unsigned char* p = (unsigned char*)d_ws;
  unsigned short* xp = (unsigned short*)p;                 p += (size_t)BATCH * TPADDED * DPAD * 2;
  unsigned short* hb = (unsigned short*)p;                 p += (size_t)BATCH * TPRIME * DPAD * 2;
  unsigned short* wT = (unsigned short*)p;                 p += (size_t)KSZ * DPAD * DPAD * 2;
  unsigned short* Ub = (unsigned short*)p;

  hipLaunchKernelGGL(gather_kernel, dim3(BATCH * TPADDED / 4), dim3(256), 0, stream,
                     ids, embed_w, xp);
  hipLaunchKernelGGL(wt_kernel, dim3(KSZ * DPAD), dim3(256), 0, stream, conv_w, wT);
  hipLaunchKernelGGL(ut_kernel, dim3(LPAD), dim3(256), 0, stream, U, Ub);
  hipLaunchKernelGGL(conv_mfma_kernel, dim3(BATCH * 33), dim3(256), 0, stream,
                     xp, wT, conv_b, hb);
  hipLaunchKernelGGL(attn_mfma_kernel, dim3(BATCH * NLB), dim3(256), 0, stream,
                     hb, Ub, fc_bias, out);
}